// Round 1
// baseline (142.580 us; speedup 1.0000x reference)
//
#include <hip/hip_runtime.h>
#include <math.h>

namespace {

constexpr int B = 64, C = 3, H = 512, W = 512;
constexpr int HW  = H * W;    // 262144 = 2^18
constexpr int CHW = C * HW;   // 786432
constexpr int NBLK = 32;      // partial-sum blocks per batch

struct Params {
  int th, tw;          // translation
  int y0, y1, x0, x1;  // cutout rect (inclusive)
  float br, sat, ctr, g;
};

// ---------------- kernel 1: partial sums of translated image ----------------
__global__ __launch_bounds__(256) void psum_kernel(
    const float* __restrict__ img, const float* __restrict__ rnd,
    float* __restrict__ psum) {
  const int b   = blockIdx.x / NBLK;
  const int blk = blockIdx.x % NBLK;
  const int th = (int)floorf(rnd[0 * B + b] * 129.0f) - 64;
  const int tw = (int)floorf(rnd[1 * B + b] * 129.0f) - 64;
  const long base = (long)b * CHW;
  constexpr int chunk = CHW / NBLK;  // 24576
  float s = 0.0f;
  for (int j = blk * chunk + (int)threadIdx.x; j < (blk + 1) * chunk; j += 256) {
    const int c   = j >> 18;          // / HW
    const int rem = j & (HW - 1);
    const int y = rem >> 9;           // / W
    const int x = rem & (W - 1);
    const int sy = y + th, sx = x + tw;
    if ((unsigned)sy < (unsigned)H && (unsigned)sx < (unsigned)W)
      s += img[base + (long)c * HW + sy * W + sx];
  }
#pragma unroll
  for (int off = 32; off > 0; off >>= 1) s += __shfl_down(s, off, 64);
  __shared__ float red[4];
  if ((threadIdx.x & 63) == 0) red[threadIdx.x >> 6] = s;
  __syncthreads();
  if (threadIdx.x == 0)
    psum[blockIdx.x] = red[0] + red[1] + red[2] + red[3];
}

// ---------------- kernel 2: reduce partials + compute per-batch params ------
__global__ __launch_bounds__(64) void finalize_kernel(
    const float* __restrict__ rnd, const float* __restrict__ psum,
    Params* __restrict__ P) {
  const int b = blockIdx.x;
  float s = (threadIdx.x < NBLK) ? psum[b * NBLK + threadIdx.x] : 0.0f;
#pragma unroll
  for (int off = 32; off > 0; off >>= 1) s += __shfl_down(s, off, 64);
  if (threadIdx.x == 0) {
    Params p;
    p.th  = (int)floorf(rnd[0 * B + b] * 129.0f) - 64;
    p.tw  = (int)floorf(rnd[1 * B + b] * 129.0f) - 64;
    p.br  = rnd[2 * B + b] - 0.5f;
    p.sat = rnd[3 * B + b] * 2.0f;
    p.ctr = rnd[4 * B + b] + 0.5f;
    const int oh = (int)floorf(rnd[5 * B + b] * 513.0f);  // h + 1 (ch even)
    const int ow = (int)floorf(rnd[6 * B + b] * 513.0f);
    p.y0 = max(0, oh - 51); p.y1 = min(H - 1, oh + 50);   // ch=102, ch/2=51
    p.x0 = max(0, ow - 51); p.x1 = min(W - 1, ow + 50);
    p.g  = s / (float)CHW + p.br;  // g_mean of post-sat image = mean(t) + br
    P[b] = p;
  }
}

// ---------------- kernel 3: fused transform ---------------------------------
__global__ __launch_bounds__(256) void aug_kernel(
    const float* __restrict__ img, const Params* __restrict__ P,
    float* __restrict__ out) {
  const int idx = blockIdx.x * 256 + threadIdx.x;  // pixel index over B*HW
  const int b   = idx >> 18;                       // / HW
  const int rem = idx & (HW - 1);
  const int y = rem >> 9;
  const int x = rem & (W - 1);
  const Params p = P[b];

  const long obase = (long)b * CHW + rem;
  // cutout: output is exactly 0 there
  if (y >= p.y0 && y <= p.y1 && x >= p.x0 && x <= p.x1) {
    out[obase]          = 0.0f;
    out[obase + HW]     = 0.0f;
    out[obase + 2 * HW] = 0.0f;
    return;
  }

  const int sy = y + p.th, sx = x + p.tw;
  float t0 = 0.0f, t1 = 0.0f, t2 = 0.0f;
  if ((unsigned)sy < (unsigned)H && (unsigned)sx < (unsigned)W) {
    const long sbase = (long)b * CHW + sy * W + sx;
    t0 = img[sbase];
    t1 = img[sbase + HW];
    t2 = img[sbase + 2 * HW];
  }
  const float mc = (t0 + t1 + t2) * (1.0f / 3.0f);
  const float br = p.br, sat = p.sat, ctr = p.ctr, g = p.g;
  // v = (t - mc)*sat + mc + br ; out = (v - g)*ctr + g
  const float v0 = (t0 - mc) * sat + mc + br;
  const float v1 = (t1 - mc) * sat + mc + br;
  const float v2 = (t2 - mc) * sat + mc + br;
  out[obase]          = (v0 - g) * ctr + g;
  out[obase + HW]     = (v1 - g) * ctr + g;
  out[obase + 2 * HW] = (v2 - g) * ctr + g;
}

}  // namespace

extern "C" void kernel_launch(void* const* d_in, const int* in_sizes, int n_in,
                              void* d_out, int out_size, void* d_ws, size_t ws_size,
                              hipStream_t stream) {
  const float* img = (const float*)d_in[0];
  const float* rnd = (const float*)d_in[1];
  float* out = (float*)d_out;

  float*  psum = (float*)d_ws;
  Params* P    = (Params*)((char*)d_ws + B * NBLK * sizeof(float));

  hipLaunchKernelGGL(psum_kernel, dim3(B * NBLK), dim3(256), 0, stream,
                     img, rnd, psum);
  hipLaunchKernelGGL(finalize_kernel, dim3(B), dim3(64), 0, stream,
                     rnd, psum, P);
  hipLaunchKernelGGL(aug_kernel, dim3((B * HW) / 256), dim3(256), 0, stream,
                     img, P, out);
}

// Round 2
// 89.643 us; speedup vs baseline: 1.5905x; 1.5905x over previous
//
#include <hip/hip_runtime.h>
#include <math.h>

typedef float f32x4 __attribute__((ext_vector_type(4)));

namespace {

constexpr int B = 64, C = 3, H = 512, W = 512;
constexpr int HW  = H * W;      // 262144 = 2^18
constexpr int CHW = C * HW;     // 786432
constexpr int NBLK = 32;        // partial-sum blocks per batch
constexpr int CHUNK4 = CHW / 4 / NBLK;  // 6144 float4 per block

struct Params {
  int th, tw;          // translation
  int y0, y1, x0, x1;  // cutout rect (inclusive)
  float br, sat, ctr, g;
};

// ---- kernel 1: window sum of source image (== sum of translated image) -----
__global__ __launch_bounds__(256) void psum_kernel(
    const float* __restrict__ img, const float* __restrict__ rnd,
    float* __restrict__ psum) {
  const int b   = blockIdx.x / NBLK;
  const int blk = blockIdx.x % NBLK;
  const int th = (int)floorf(rnd[0 * B + b] * 129.0f) - 64;
  const int tw = (int)floorf(rnd[1 * B + b] * 129.0f) - 64;
  // source-frame window contributing to the translated image
  const int ylo = max(0, th), yhi = min(H - 1, H - 1 + th);
  const int xlo = max(0, tw), xhi = min(W - 1, W - 1 + tw);
  const long base = (long)b * CHW;
  float s = 0.0f;
  for (int j4 = blk * CHUNK4 + (int)threadIdx.x; j4 < (blk + 1) * CHUNK4;
       j4 += 256) {
    const int c   = j4 >> 16;          // / (HW/4)
    const int rem = j4 & 65535;
    const int y   = rem >> 7;          // / (W/4)
    if (y < ylo || y > yhi) continue;  // whole row outside window: no load
    const int x4 = (rem & 127) << 2;
    const f32x4 v =
        *(const f32x4*)(img + base + (long)c * HW + (long)y * W + x4);
#pragma unroll
    for (int e = 0; e < 4; ++e) {
      const int x = x4 + e;
      s += (x >= xlo && x <= xhi) ? v[e] : 0.0f;
    }
  }
#pragma unroll
  for (int off = 32; off > 0; off >>= 1) s += __shfl_down(s, off, 64);
  __shared__ float red[4];
  if ((threadIdx.x & 63) == 0) red[threadIdx.x >> 6] = s;
  __syncthreads();
  if (threadIdx.x == 0)
    psum[blockIdx.x] = red[0] + red[1] + red[2] + red[3];
}

// ---- kernel 2: reduce partials + per-batch params --------------------------
__global__ __launch_bounds__(64) void finalize_kernel(
    const float* __restrict__ rnd, const float* __restrict__ psum,
    Params* __restrict__ P) {
  const int b = blockIdx.x;
  float s = (threadIdx.x < NBLK) ? psum[b * NBLK + threadIdx.x] : 0.0f;
#pragma unroll
  for (int off = 32; off > 0; off >>= 1) s += __shfl_down(s, off, 64);
  if (threadIdx.x == 0) {
    Params p;
    p.th  = (int)floorf(rnd[0 * B + b] * 129.0f) - 64;
    p.tw  = (int)floorf(rnd[1 * B + b] * 129.0f) - 64;
    p.br  = rnd[2 * B + b] - 0.5f;
    p.sat = rnd[3 * B + b] * 2.0f;
    p.ctr = rnd[4 * B + b] + 0.5f;
    const int oh = (int)floorf(rnd[5 * B + b] * 513.0f);  // ch=102 even
    const int ow = (int)floorf(rnd[6 * B + b] * 513.0f);
    p.y0 = max(0, oh - 51); p.y1 = min(H - 1, oh + 50);
    p.x0 = max(0, ow - 51); p.x1 = min(W - 1, ow + 50);
    p.g  = s / (float)CHW + p.br;  // g_mean of post-sat image = mean(t)+br
    P[b] = p;
  }
}

// ---- kernel 3: fused transform, 4 pixels (x) per thread --------------------
__global__ __launch_bounds__(256) void aug_kernel(
    const float* __restrict__ img, const Params* __restrict__ P,
    float* __restrict__ out) {
  const int idx4 = blockIdx.x * 256 + threadIdx.x;  // over B*HW/4
  const int b    = idx4 >> 16;                      // / (HW/4)
  const int rem  = idx4 & 65535;
  const int y    = rem >> 7;
  const int x0   = (rem & 127) << 2;
  const Params p = P[b];
  const long obase = (long)b * CHW + ((long)rem << 2);

  // translated read (zero outside source bounds)
  f32x4 t0 = {0, 0, 0, 0}, t1 = {0, 0, 0, 0}, t2 = {0, 0, 0, 0};
  const int sy  = y + p.th;
  const int sxa = x0 + p.tw;
  if ((unsigned)sy < (unsigned)H) {
    const long sb = (long)b * CHW + (long)sy * W + sxa;
    if (sxa >= 0 && sxa <= W - 4) {  // 4B-aligned dwordx4: OK on CDNA
      t0 = *(const f32x4*)(img + sb);
      t1 = *(const f32x4*)(img + sb + HW);
      t2 = *(const f32x4*)(img + sb + 2 * HW);
    } else {
#pragma unroll
      for (int e = 0; e < 4; ++e) {
        const int sx = sxa + e;
        if ((unsigned)sx < (unsigned)W) {
          t0[e] = img[sb + e];
          t1[e] = img[sb + HW + e];
          t2[e] = img[sb + 2 * HW + e];
        }
      }
    }
  }

  const f32x4 mc = (t0 + t1 + t2) * (1.0f / 3.0f);
  const float br = p.br, sat = p.sat, ctr = p.ctr, g = p.g;
  // v = (t - mc)*sat + mc + br ; o = (v - g)*ctr + g
  f32x4 o0 = ((t0 - mc) * sat + mc + (br - g)) * ctr + g;
  f32x4 o1 = ((t1 - mc) * sat + mc + (br - g)) * ctr + g;
  f32x4 o2 = ((t2 - mc) * sat + mc + (br - g)) * ctr + g;

  // cutout: exact zeros
  if (y >= p.y0 && y <= p.y1) {
#pragma unroll
    for (int e = 0; e < 4; ++e) {
      const int x = x0 + e;
      if (x >= p.x0 && x <= p.x1) { o0[e] = 0.0f; o1[e] = 0.0f; o2[e] = 0.0f; }
    }
  }

  // nontemporal stores: don't evict img from L2/L3
  __builtin_nontemporal_store(o0, (f32x4*)(out + obase));
  __builtin_nontemporal_store(o1, (f32x4*)(out + obase + HW));
  __builtin_nontemporal_store(o2, (f32x4*)(out + obase + 2 * HW));
}

}  // namespace

extern "C" void kernel_launch(void* const* d_in, const int* in_sizes, int n_in,
                              void* d_out, int out_size, void* d_ws, size_t ws_size,
                              hipStream_t stream) {
  const float* img = (const float*)d_in[0];
  const float* rnd = (const float*)d_in[1];
  float* out = (float*)d_out;

  float*  psum = (float*)d_ws;
  Params* P    = (Params*)((char*)d_ws + B * NBLK * sizeof(float));

  hipLaunchKernelGGL(psum_kernel, dim3(B * NBLK), dim3(256), 0, stream,
                     img, rnd, psum);
  hipLaunchKernelGGL(finalize_kernel, dim3(B), dim3(64), 0, stream,
                     rnd, psum, P);
  hipLaunchKernelGGL(aug_kernel, dim3((B * HW) / 4 / 256), dim3(256), 0, stream,
                     img, P, out);
}